// Round 13
// baseline (446.140 us; speedup 1.0000x reference)
//
#include <hip/hip_runtime.h>
#include <hip/hip_bf16.h>

#define I_SZ 834
#define H_SZ 190
#define F_SZ 250
#define O_SZ 512
#define T_SZ 256
#define K_SZ 1024   // I+H
#define NW   47500  // F*H: Wupd flat IS W3[1024][47500] row-major

// Abf2 layout: value A[t][k] (bf16 of concat(x_t,h_t)) lives at
//   (k>>3)*2048 + t*8 + (k&7)   -> b128 fragment loads are 256-B coalesced,
//   and 4 consecutive k-slabs = 16 KB contiguous (one K-stage of staging).

typedef __attribute__((ext_vector_type(8))) short short8;
typedef __attribute__((ext_vector_type(4))) float f32x4;

__device__ __forceinline__ short f2bf(float f) {
    union { __hip_bfloat16 h; short s; } u;
    u.h = __float2bfloat16(f);
    return u.s;
}
__device__ __forceinline__ float bf2f(short s) {
    union { short s; __hip_bfloat16 h; } u;
    u.s = s;
    return __bfloat162float(u.h);
}

// async global->LDS, 16B per lane; LDS dest = wave-uniform base + lane*16
__device__ __forceinline__ void gll16(const void* g, void* l) {
    __builtin_amdgcn_global_load_lds(
        (const __attribute__((address_space(1))) void*)g,
        (__attribute__((address_space(3))) void*)l, 16, 0, 0);
}

// LDS-only barrier: drain lgkm (ds ops) but NOT vmcnt.
__device__ __forceinline__ void lds_barrier() {
    asm volatile("s_waitcnt lgkmcnt(0)" ::: "memory");
    __builtin_amdgcn_s_barrier();
}

// branch-free tanh: 1 - 2/(e^{2x}+1); exp overflow/underflow saturate to +/-1
__device__ __forceinline__ float fast_tanh(float x) {
    const float e = __expf(2.f * x);
    return 1.f - 2.f / (e + 1.f);
}

// -------- K2b: x-part of Abf2 + zero pad k in [834,864) ---------------------
__global__ void __launch_bounds__(256) k2b_buildAx(const float* __restrict__ x,
                                                   short* __restrict__ Abf2) {
    int t = blockIdx.x;
    for (int i = threadIdx.x; i < I_SZ; i += 256)
        Abf2[(i >> 3) * (T_SZ * 8) + t * 8 + (i & 7)] = f2bf(x[t * I_SZ + i]);
    for (int i = I_SZ + threadIdx.x; i < 864; i += 256)
        Abf2[(i >> 3) * (T_SZ * 8) + t * 8 + (i & 7)] = 0;
}

// -------- K1: P^T[h][t] = Wx^T @ x^T via MFMA (12 blocks x 4 waves) ---------
__global__ void __launch_bounds__(256) k1_mfma(const short* __restrict__ Abf2,
                                               const float* __restrict__ Wrnn,
                                               const float* __restrict__ brnn,
                                               float* __restrict__ P) {
    const int tid = threadIdx.x;
    const int bh = blockIdx.x;
    const int w = tid >> 6, l = tid & 63;
    const int l15 = l & 15, lg = l >> 4;
    const int h = bh * 16 + l15;
    const int hc = (h < H_SZ) ? h : H_SZ - 1;

    f32x4 acc[4];
    #pragma unroll
    for (int tt = 0; tt < 4; ++tt) acc[tt] = (f32x4){0.f, 0.f, 0.f, 0.f};

    for (int ks = 0; ks < 27; ++ks) {       // K = 864 (zero-padded past 834)
        short8 afr;
        #pragma unroll
        for (int e = 0; e < 8; ++e) {
            const int kk = ks * 32 + lg * 8 + e;
            float v = (kk < I_SZ && h < H_SZ) ? Wrnn[hc * K_SZ + H_SZ + kk] : 0.f;
            afr[e] = f2bf(v);
        }
        #pragma unroll
        for (int tt = 0; tt < 4; ++tt) {
            const short* ap = Abf2 + (size_t)(ks * 4 + lg) * (T_SZ * 8)
                                   + (size_t)(w * 64 + tt * 16 + l15) * 8;
            short8 bfr = *reinterpret_cast<const short8*>(ap);
            acc[tt] = __builtin_amdgcn_mfma_f32_16x16x32_bf16(afr, bfr, acc[tt], 0, 0, 0);
        }
    }
    #pragma unroll
    for (int tt = 0; tt < 4; ++tt) {
        const int t = w * 64 + tt * 16 + l15;
        #pragma unroll
        for (int r = 0; r < 4; ++r) {
            const int hrow = bh * 16 + lg * 4 + r;
            if (hrow < H_SZ) P[t * H_SZ + hrow] = acc[tt][r] + brnn[hrow];
        }
    }
}

// -------- K2 v7: MFMA scan, 4 waves x 48 n-cols, full k, no masking ---------
// B[6][3] = 18 frags; unified VGPR/AGPR file + launch_bounds(256,1) gives
// 512-reg budget (R10's spill came from a 256-reg ceiling). A-frags are
// UNMASKED broadcasts: all 16 A-rows = h, so every C row equals h.B -- no
// cndmask needed. Two independent 3-deep MFMA chains per n-tile (even/odd kt)
// halve the AGPR-forwarding latency. One lgkm-only barrier per step.
// LDS issue: 4 waves x 6 ds_read_b128 = 24/step (vs 72 in v6).
__global__ void __launch_bounds__(256, 1) k2_scan(const float* __restrict__ Wrnn,
                                                  const float* __restrict__ h0,
                                                  const float* __restrict__ P,
                                                  float* __restrict__ S,
                                                  short* __restrict__ Abf2) {
    __shared__ __align__(16) short hlds[2][192];
    const int tid = threadIdx.x;
    const int w = tid >> 6, l = tid & 63;
    const int l15 = l & 15, lg = l >> 4;

    // one-time: this wave's Whh^T fragments (18 x 4 regs)
    short8 B[6][3];
    #pragma unroll
    for (int kt = 0; kt < 6; ++kt) {
        #pragma unroll
        for (int nt = 0; nt < 3; ++nt) {
            const int n = w * 48 + nt * 16 + l15;
            short8 bf;
            #pragma unroll
            for (int e = 0; e < 8; ++e) {
                const int kk = kt * 32 + lg * 8 + e;
                float v = (n < H_SZ && kk < H_SZ) ? Wrnn[n * K_SZ + kk] : 0.f;
                bf[e] = f2bf(v);
            }
            B[kt][nt] = bf;
        }
    }
    if (tid < 192) {
        hlds[0][tid] = f2bf((tid < H_SZ) ? h0[tid] : 0.f);
        hlds[1][tid] = 0;                   // pad slots 190,191 stay 0 forever
    }
    float Srun[3] = {0.f, 0.f, 0.f};
    float pc[3];
    #pragma unroll
    for (int nt = 0; nt < 3; ++nt) {
        const int n = w * 48 + nt * 16 + l15;
        pc[nt] = (l < 16 && n < H_SZ) ? P[n] : 0.f;
    }
    lds_barrier();

    int rb = 0;
    #pragma unroll 1
    for (int t = 0; t < T_SZ; ++t) {
        // a-frags: pure broadcast, NO masking (all A rows = h)
        short8 a[6];
        #pragma unroll
        for (int kt = 0; kt < 6; ++kt)
            a[kt] = *reinterpret_cast<const short8*>(&hlds[rb][kt * 32 + lg * 8]);
        float pn[3];
        #pragma unroll
        for (int nt = 0; nt < 3; ++nt) {
            const int n = w * 48 + nt * 16 + l15;
            pn[nt] = (t + 1 < T_SZ && l < 16 && n < H_SZ) ? P[(t + 1) * H_SZ + n] : 0.f;
        }
        // two independent 3-deep chains per n-tile
        f32x4 cA[3], cB[3];
        #pragma unroll
        for (int nt = 0; nt < 3; ++nt) {
            const f32x4 z4 = {0.f, 0.f, 0.f, 0.f};
            f32x4 u = __builtin_amdgcn_mfma_f32_16x16x32_bf16(a[0], B[0][nt], z4, 0, 0, 0);
            f32x4 v = __builtin_amdgcn_mfma_f32_16x16x32_bf16(a[1], B[1][nt], z4, 0, 0, 0);
            u = __builtin_amdgcn_mfma_f32_16x16x32_bf16(a[2], B[2][nt], u, 0, 0, 0);
            v = __builtin_amdgcn_mfma_f32_16x16x32_bf16(a[3], B[3][nt], v, 0, 0, 0);
            u = __builtin_amdgcn_mfma_f32_16x16x32_bf16(a[4], B[4][nt], u, 0, 0, 0);
            v = __builtin_amdgcn_mfma_f32_16x16x32_bf16(a[5], B[5][nt], v, 0, 0, 0);
            cA[nt] = u; cB[nt] = v;
        }
        if (l < 16) {
            #pragma unroll
            for (int nt = 0; nt < 3; ++nt) {
                const int n = w * 48 + nt * 16 + l15;
                if (n < H_SZ) {
                    const float v = fast_tanh(cA[nt][0] + cB[nt][0] + pc[nt]);
                    S[t * H_SZ + n] = Srun[nt];     // prefix EXCLUDING current
                    const int k = I_SZ + n;
                    Abf2[(k >> 3) * (T_SZ * 8) + t * 8 + (k & 7)] = f2bf(v);
                    hlds[rb ^ 1][n] = f2bf(v);      // write buf != read buf
                    Srun[nt] += v;
                }
            }
        }
        lds_barrier();                      // single LDS-only barrier per step
        rb ^= 1;
        #pragma unroll
        for (int nt = 0; nt < 3; ++nt) pc[nt] = pn[nt];
    }
}

// -------- K3 v5: 2-phase gll-staged MFMA GEMM (zero global loads in K-loop) -
__global__ void __launch_bounds__(512) k3_mfma(const float* __restrict__ Wupd,
                                               const short* __restrict__ Abf2,
                                               const float* __restrict__ S,
                                               float* __restrict__ zprime) {
    __shared__ __align__(16) float Wlds[2][4096];    // [32 k][128 n] fp32
    __shared__ __align__(16) short Alds[2][8192];    // [4 g][256 t][8 k] bf16
    __shared__ float part[2][256];
    const int tid = threadIdx.x;
    const int bn0 = blockIdx.x * 128;
    const int l = tid & 63, wv = tid >> 6;
    const int l15 = l & 15, lg = l >> 4;

    part[tid >> 8][tid & 255] = 0.f;

    const char* src[4];
    long long stp[4];
    int cloc[4];
    #pragma unroll
    for (int i = 0; i < 4; ++i) {
        const int c = wv * 4 + i;
        cloc[i] = c;
        if (c < 16) {
            const int k = c * 2 + (l >> 5);          // 0..31
            const int n = (l & 31) * 4;              // 0..124
            const bool ok = (bn0 + n + 4) <= NW;     // NW % 4 == 0
            src[i] = (const char*)(Wupd + (size_t)k * NW + (ok ? (size_t)(bn0 + n) : 0));
            stp[i] = (long long)32 * NW * 4;
        } else {
            src[i] = (const char*)(Abf2 + (size_t)(c - 16) * 512 + (size_t)l * 8);
            stp[i] = 16384;
        }
    }

    f32x4 acc[16];
    #pragma unroll
    for (int tt = 0; tt < 16; ++tt) acc[tt] = (f32x4){0.f, 0.f, 0.f, 0.f};

    #pragma unroll
    for (int i = 0; i < 4; ++i) {
        void* dst = (cloc[i] < 16) ? (void*)&Wlds[0][cloc[i] * 256]
                                   : (void*)&Alds[0][(cloc[i] - 16) * 512];
        gll16(src[i], dst);
        src[i] += stp[i];
    }
    __syncthreads();

    int cur = 0;
    #pragma unroll 1
    for (int s = 0; s < 32; ++s) {
        if (s + 1 < 32) {                            // issue next stage FIRST
            #pragma unroll
            for (int i = 0; i < 4; ++i) {
                void* dst = (cloc[i] < 16) ? (void*)&Wlds[cur ^ 1][cloc[i] * 256]
                                           : (void*)&Alds[cur ^ 1][(cloc[i] - 16) * 512];
                gll16(src[i], dst);
                src[i] += stp[i];
            }
        }
        short8 afr;
        #pragma unroll
        for (int e = 0; e < 8; ++e)
            afr[e] = f2bf(Wlds[cur][(lg * 8 + e) * 128 + wv * 16 + l15]);
        #pragma unroll
        for (int tt = 0; tt < 16; ++tt) {
            short8 bfr = *reinterpret_cast<const short8*>(
                &Alds[cur][((size_t)lg * 256 + tt * 16 + l15) * 8]);
            acc[tt] = __builtin_amdgcn_mfma_f32_16x16x32_bf16(afr, bfr, acc[tt], 0, 0, 0);
        }
        __syncthreads();
        cur ^= 1;
    }

    const int jlo = bn0 / H_SZ;
    #pragma unroll
    for (int tt = 0; tt < 16; ++tt) {
        float p0 = 0.f, p1 = 0.f;
        const int t = tt * 16 + l15;
        #pragma unroll
        for (int r = 0; r < 4; ++r) {
            const int n = bn0 + wv * 16 + lg * 4 + r;
            const bool ok = n < NW;
            const int nc = ok ? n : NW - 1;
            const int j = nc / H_SZ;
            const int h = nc - j * H_SZ;
            const float sv = S[t * H_SZ + h];
            const float prod = ok ? acc[tt][r] * sv : 0.f;
            if (j == jlo) p0 += prod; else p1 += prod;
        }
        p0 += __shfl_xor(p0, 16, 64); p0 += __shfl_xor(p0, 32, 64);
        p1 += __shfl_xor(p1, 16, 64); p1 += __shfl_xor(p1, 32, 64);
        if (lg == 0) {
            if (p0 != 0.f) atomicAdd(&part[0][t], p0);
            if (p1 != 0.f) atomicAdd(&part[1][t], p1);
        }
    }
    __syncthreads();
    {
        const int b = tid >> 8, t = tid & 255;
        const int j = jlo + b;
        const float v = part[b][t];
        if (j < F_SZ && v != 0.f) atomicAdd(&zprime[t * F_SZ + j], v);
    }
}

// -------- K4a v2: 256 one-wave blocks (16 j-tiles x 16 t-tiles) -------------
__global__ void __launch_bounds__(64) k4a_mfma(const short* __restrict__ Abf2,
                                               const float* __restrict__ W1,
                                               const float* __restrict__ bupd,
                                               const float* __restrict__ b1,
                                               const float* __restrict__ zprime,
                                               short* __restrict__ ysb) {
    const int l = threadIdx.x;
    const int j0 = (blockIdx.x & 15) * 16;
    const int th = blockIdx.x >> 4;           // 0..15: 16 t each
    const int l15 = l & 15, lg = l >> 4;
    const int jc = j0 + l15;
    const int jl = (jc < F_SZ) ? jc : F_SZ - 1;

    f32x4 acc1 = {0.f, 0.f, 0.f, 0.f};
    f32x4 acch = {0.f, 0.f, 0.f, 0.f};
    f32x4 accl = {0.f, 0.f, 0.f, 0.f};

    for (int ks = 0; ks < 32; ++ks) {
        short8 a1, ah, al;
        #pragma unroll
        for (int e = 0; e < 8; ++e) {
            const int kk = ks * 32 + lg * 8 + e;
            a1[e] = f2bf(W1[kk * F_SZ + jl]);
            const float bu = bupd[kk * F_SZ + jl];
            const short hi = f2bf(bu);
            ah[e] = hi;
            al[e] = f2bf(bu - bf2f(hi));
        }
        const short* ap = Abf2 + (size_t)(ks * 4 + lg) * (T_SZ * 8)
                               + (size_t)(th * 16 + l15) * 8;
        short8 bfr = *reinterpret_cast<const short8*>(ap);
        acc1 = __builtin_amdgcn_mfma_f32_16x16x32_bf16(a1, bfr, acc1, 0, 0, 0);
        acch = __builtin_amdgcn_mfma_f32_16x16x32_bf16(ah, bfr, acch, 0, 0, 0);
        accl = __builtin_amdgcn_mfma_f32_16x16x32_bf16(al, bfr, accl, 0, 0, 0);
    }
    const float scale = 1.0507009873554805f, alpha = 1.6732632423543772f;
    const int t = th * 16 + l15;              // C col
    #pragma unroll
    for (int r = 0; r < 4; ++r) {
        const int jr = j0 + lg * 4 + r;       // C row
        short sv = 0;
        if (jr < F_SZ) {
            const float d2 = acch[r] + accl[r];
            float z = zprime[t * F_SZ + jr] + acc1[r] + (float)t * d2 + b1[jr];
            float y = z > 0.f ? scale * z : scale * alpha * (expf(z) - 1.f);
            sv = f2bf(y);
        }
        ysb[(jr >> 3) * (T_SZ * 8) + t * 8 + (jr & 7)] = sv;   // jr < 256 always
    }
}

// -------- K4b v2: 256 one-wave blocks (32 o-tiles x 8 t-tiles of 32 t) ------
__global__ void __launch_bounds__(64) k4b_mfma(const short* __restrict__ ysb,
                                               const float* __restrict__ W2,
                                               const float* __restrict__ b2,
                                               float* __restrict__ out) {
    const int l = threadIdx.x;
    const int o0 = (blockIdx.x & 31) * 16;
    const int th = blockIdx.x >> 5;           // 0..7: 32 t each
    const int l15 = l & 15, lg = l >> 4;
    const int o = o0 + l15;

    f32x4 acc[2];
    acc[0] = (f32x4){0.f, 0.f, 0.f, 0.f};
    acc[1] = (f32x4){0.f, 0.f, 0.f, 0.f};

    for (int ks = 0; ks < 8; ++ks) {          // K = 256 (250 real + 6 zero)
        short8 afr;
        #pragma unroll
        for (int e = 0; e < 8; ++e) {
            const int kk = ks * 32 + lg * 8 + e;
            afr[e] = (kk < F_SZ) ? f2bf(W2[kk * O_SZ + o]) : (short)0;
        }
        #pragma unroll
        for (int tt = 0; tt < 2; ++tt) {
            const short* ap = ysb + (size_t)(ks * 4 + lg) * (T_SZ * 8)
                                  + (size_t)(th * 32 + tt * 16 + l15) * 8;
            short8 bfr = *reinterpret_cast<const short8*>(ap);
            acc[tt] = __builtin_amdgcn_mfma_f32_16x16x32_bf16(afr, bfr, acc[tt], 0, 0, 0);
        }
    }
    #pragma unroll
    for (int tt = 0; tt < 2; ++tt) {
        const int t = th * 32 + tt * 16 + l15;
        #pragma unroll
        for (int r = 0; r < 4; ++r) {
            const int oo = o0 + lg * 4 + r;
            out[t * O_SZ + oo] = acc[tt][r] + b2[oo];
        }
    }
}

extern "C" void kernel_launch(void* const* d_in, const int* in_sizes, int n_in,
                              void* d_out, int out_size, void* d_ws, size_t ws_size,
                              hipStream_t stream) {
    const float* x    = (const float*)d_in[0];
    const float* h0   = (const float*)d_in[1];
    const float* Wrnn = (const float*)d_in[2];
    const float* brnn = (const float*)d_in[3];
    const float* Wupd = (const float*)d_in[4];
    const float* bupd = (const float*)d_in[5];
    const float* W1   = (const float*)d_in[6];
    const float* b1   = (const float*)d_in[7];
    const float* W2   = (const float*)d_in[8];
    const float* b2   = (const float*)d_in[9];
    float* out = (float*)d_out;

    float* ws = (float*)d_ws;
    float* P      = ws;                              // 48640
    float* h_all  = P + T_SZ * H_SZ;                 // 48640 (slot kept, unused)
    float* S      = h_all + T_SZ * H_SZ;             // 48640
    float* zprime = S + T_SZ * H_SZ;                 // 64000
    short* Abf2   = (short*)(zprime + T_SZ * F_SZ);  // 262144 shorts
    short* ysb    = Abf2 + 262144;                   // 65536 shorts (128 KB)

    hipMemsetAsync(zprime, 0, T_SZ * F_SZ * sizeof(float), stream);
    k2b_buildAx<<<T_SZ, 256, 0, stream>>>(x, Abf2);
    k1_mfma    <<<12,   256, 0, stream>>>(Abf2, Wrnn, brnn, P);
    k2_scan    <<<1,    256, 0, stream>>>(Wrnn, h0, P, S, Abf2);
    k3_mfma    <<<372,  512, 0, stream>>>(Wupd, Abf2, S, zprime);
    k4a_mfma   <<<256,  64,  0, stream>>>(Abf2, W1, bupd, b1, zprime, ysb);
    k4b_mfma   <<<256,  64,  0, stream>>>(ysb, W2, b2, out);
}

// Round 15
// 306.692 us; speedup vs baseline: 1.4547x; 1.4547x over previous
//
#include <hip/hip_runtime.h>
#include <hip/hip_bf16.h>

#define I_SZ 834
#define H_SZ 190
#define F_SZ 250
#define O_SZ 512
#define T_SZ 256
#define K_SZ 1024   // I+H
#define NW   47500  // F*H: Wupd flat IS W3[1024][47500] row-major

// Abf2 layout: value A[t][k] (bf16 of concat(x_t,h_t)) lives at
//   (k>>3)*2048 + t*8 + (k&7)   -> b128 fragment loads are 256-B coalesced,
//   and 4 consecutive k-slabs = 16 KB contiguous (one K-stage of staging).

typedef __attribute__((ext_vector_type(8))) short short8;
typedef __attribute__((ext_vector_type(4))) float f32x4;

__device__ __forceinline__ short f2bf(float f) {
    union { __hip_bfloat16 h; short s; } u;
    u.h = __float2bfloat16(f);
    return u.s;
}
__device__ __forceinline__ float bf2f(short s) {
    union { short s; __hip_bfloat16 h; } u;
    u.s = s;
    return __bfloat162float(u.h);
}

// async global->LDS, 16B per lane; LDS dest = wave-uniform base + lane*16
__device__ __forceinline__ void gll16(const void* g, void* l) {
    __builtin_amdgcn_global_load_lds(
        (const __attribute__((address_space(1))) void*)g,
        (__attribute__((address_space(3))) void*)l, 16, 0, 0);
}

// LDS-only barrier: drain lgkm (ds ops) but NOT vmcnt.
__device__ __forceinline__ void lds_barrier() {
    asm volatile("s_waitcnt lgkmcnt(0)" ::: "memory");
    __builtin_amdgcn_s_barrier();
}

// branch-free tanh: 1 - 2/(e^{2x}+1); exp overflow/underflow saturate to +/-1
__device__ __forceinline__ float fast_tanh(float x) {
    const float e = __expf(2.f * x);
    return 1.f - 2.f / (e + 1.f);
}

// -------- K2b: x->Abf2 slab, zero pad, zero zprime, pad W1/bupd to 256 cols -
__global__ void __launch_bounds__(256) k2b_buildAx(const float* __restrict__ x,
                                                   const float* __restrict__ W1,
                                                   const float* __restrict__ bupd,
                                                   short* __restrict__ Abf2,
                                                   float* __restrict__ zprime,
                                                   float* __restrict__ W1p,
                                                   float* __restrict__ bupdp) {
    const int t = blockIdx.x;
    for (int i = threadIdx.x; i < I_SZ; i += 256)
        Abf2[(i >> 3) * (T_SZ * 8) + t * 8 + (i & 7)] = f2bf(x[t * I_SZ + i]);
    for (int i = I_SZ + threadIdx.x; i < 864; i += 256)
        Abf2[(i >> 3) * (T_SZ * 8) + t * 8 + (i & 7)] = 0;
    for (int j = threadIdx.x; j < F_SZ; j += 256)
        zprime[t * F_SZ + j] = 0.f;
    // pad W1/bupd: rows 4t..4t+3, 256 cols (250 real + 6 zero)
    const int c = threadIdx.x;
    #pragma unroll
    for (int rr = 0; rr < 4; ++rr) {
        const int r = t * 4 + rr;           // 0..1023
        const float w1v = (c < F_SZ) ? W1[r * F_SZ + c] : 0.f;
        const float buv = (c < F_SZ) ? bupd[r * F_SZ + c] : 0.f;
        W1p[r * 256 + c] = w1v;
        bupdp[r * 256 + c] = buv;
    }
}

// -------- K1: P^T[h][t] = Wx^T @ x^T via MFMA (12 blocks x 4 waves) ---------
__global__ void __launch_bounds__(256) k1_mfma(const short* __restrict__ Abf2,
                                               const float* __restrict__ Wrnn,
                                               const float* __restrict__ brnn,
                                               float* __restrict__ P) {
    const int tid = threadIdx.x;
    const int bh = blockIdx.x;
    const int w = tid >> 6, l = tid & 63;
    const int l15 = l & 15, lg = l >> 4;
    const int h = bh * 16 + l15;
    const int hc = (h < H_SZ) ? h : H_SZ - 1;

    f32x4 acc[4];
    #pragma unroll
    for (int tt = 0; tt < 4; ++tt) acc[tt] = (f32x4){0.f, 0.f, 0.f, 0.f};

    for (int ks = 0; ks < 27; ++ks) {       // K = 864 (zero-padded past 834)
        short8 afr;
        #pragma unroll
        for (int e = 0; e < 8; ++e) {
            const int kk = ks * 32 + lg * 8 + e;
            float v = (kk < I_SZ && h < H_SZ) ? Wrnn[hc * K_SZ + H_SZ + kk] : 0.f;
            afr[e] = f2bf(v);
        }
        #pragma unroll
        for (int tt = 0; tt < 4; ++tt) {
            const short* ap = Abf2 + (size_t)(ks * 4 + lg) * (T_SZ * 8)
                                   + (size_t)(w * 64 + tt * 16 + l15) * 8;
            short8 bfr = *reinterpret_cast<const short8*>(ap);
            acc[tt] = __builtin_amdgcn_mfma_f32_16x16x32_bf16(afr, bfr, acc[tt], 0, 0, 0);
        }
    }
    #pragma unroll
    for (int tt = 0; tt < 4; ++tt) {
        const int t = w * 64 + tt * 16 + l15;
        #pragma unroll
        for (int r = 0; r < 4; ++r) {
            const int hrow = bh * 16 + lg * 4 + r;
            if (hrow < H_SZ) P[t * H_SZ + hrow] = acc[tt][r] + brnn[hrow];
        }
    }
}

// -------- K2 v6 (round-12 validated, 167 us): 12 waves x 16 n-cols ----------
__global__ void __launch_bounds__(768, 1) k2_scan(const float* __restrict__ Wrnn,
                                                  const float* __restrict__ h0,
                                                  const float* __restrict__ P,
                                                  float* __restrict__ S,
                                                  short* __restrict__ Abf2) {
    __shared__ __align__(16) short hlds[2][192];
    const int tid = threadIdx.x;
    const int w = tid >> 6, l = tid & 63;
    const int l15 = l & 15, lg = l >> 4;
    const short8 zs = {0, 0, 0, 0, 0, 0, 0, 0};
    const int n = w * 16 + l15;             // wave w owns n-cols [w*16, w*16+16)
    const bool nok = n < H_SZ;

    short8 B[6];
    #pragma unroll
    for (int kt = 0; kt < 6; ++kt) {
        short8 bf = zs;
        #pragma unroll
        for (int e = 0; e < 8; ++e) {
            const int kk = kt * 32 + lg * 8 + e;
            float v = (nok && kk < H_SZ) ? Wrnn[n * K_SZ + kk] : 0.f;
            bf[e] = f2bf(v);
        }
        B[kt] = bf;
    }
    if (tid < 192) {
        hlds[0][tid] = f2bf((tid < H_SZ) ? h0[tid] : 0.f);
        hlds[1][tid] = 0;                   // pad slots 190,191 stay 0 forever
    }
    float Srun = 0.f;
    float pc = (l < 16 && nok) ? P[n] : 0.f;
    lds_barrier();

    int rb = 0;
    #pragma unroll 1
    for (int t = 0; t < T_SZ; ++t) {
        short8 a[6];
        #pragma unroll
        for (int kt = 0; kt < 6; ++kt) {
            short8 ar = *reinterpret_cast<const short8*>(&hlds[rb][kt * 32 + lg * 8]);
            a[kt] = (l15 == 0) ? ar : zs;
        }
        const float pn = (t + 1 < T_SZ && l < 16 && nok) ? P[(t + 1) * H_SZ + n] : 0.f;
        f32x4 c[6];
        #pragma unroll
        for (int kt = 0; kt < 6; ++kt) {
            const f32x4 z4 = {0.f, 0.f, 0.f, 0.f};
            c[kt] = __builtin_amdgcn_mfma_f32_16x16x32_bf16(a[kt], B[kt], z4, 0, 0, 0);
        }
        if (l < 16 && nok) {
            const float s = ((c[0][0] + c[1][0]) + (c[2][0] + c[3][0]))
                          + (c[4][0] + c[5][0]) + pc;
            const float v = fast_tanh(s);
            S[t * H_SZ + n] = Srun;         // prefix EXCLUDING current step
            const int k = I_SZ + n;
            Abf2[(k >> 3) * (T_SZ * 8) + t * 8 + (k & 7)] = f2bf(v);
            hlds[rb ^ 1][n] = f2bf(v);      // write buffer != read buffer
            Srun += v;
        }
        lds_barrier();                      // single LDS-only barrier per step
        rb ^= 1;
        pc = pn;
    }
}

// -------- K3 v6b: staged MFMA GEMM; blocks 0..371 = Wupd (S-contract fused),
// blocks 372..377 = W1p / bupdp_hi / bupdp_lo (padded, stride 256 -> every
// 4-col staging chunk valid; r14 bug was 250%4!=0 with the unpadded source).
__global__ void __launch_bounds__(512) k3_mfma(const float* __restrict__ Wupd,
                                               const float* __restrict__ W1p,
                                               const float* __restrict__ bupdp,
                                               const short* __restrict__ Abf2,
                                               const float* __restrict__ S,
                                               float* __restrict__ zprime,
                                               float* __restrict__ d1,
                                               float* __restrict__ d2h,
                                               float* __restrict__ d2l) {
    __shared__ __align__(16) float Wlds[2][4096];    // [32 k][128 n] fp32
    __shared__ __align__(16) short Alds[2][8192];    // [4 g][256 t][8 k] bf16
    __shared__ float part[2][256];
    const int tid = threadIdx.x;
    const int bid = blockIdx.x;
    const bool mainb = bid < 372;
    const int role = mainb ? 0 : (bid - 372);        // 0,1:W1  2,3:hi  4,5:lo
    const int mat  = role >> 1;
    const bool isLo = (!mainb) && (mat == 2);
    const float* Wsrc = mainb ? Wupd : ((mat == 0) ? W1p : bupdp);
    const int stride  = mainb ? NW : 256;
    const int ncols   = mainb ? NW : 256;
    const int bn0     = mainb ? bid * 128 : (role & 1) * 128;
    const int l = tid & 63, wv = tid >> 6;
    const int l15 = l & 15, lg = l >> 4;

    part[tid >> 8][tid & 255] = 0.f;

    const char* src[4];
    long long stp[4];
    int cloc[4];
    #pragma unroll
    for (int i = 0; i < 4; ++i) {
        const int c = wv * 4 + i;
        cloc[i] = c;
        if (c < 16) {
            const int k = c * 2 + (l >> 5);          // 0..31
            const int n = (l & 31) * 4;              // 0..124
            const bool ok = (bn0 + n + 4) <= ncols;  // ncols % 4 == 0 both paths
            src[i] = (const char*)(Wsrc + (size_t)k * stride + (ok ? (size_t)(bn0 + n) : 0));
            stp[i] = (long long)32 * stride * 4;
        } else {
            src[i] = (const char*)(Abf2 + (size_t)(c - 16) * 512 + (size_t)l * 8);
            stp[i] = 16384;
        }
    }

    f32x4 acc[16];
    #pragma unroll
    for (int tt = 0; tt < 16; ++tt) acc[tt] = (f32x4){0.f, 0.f, 0.f, 0.f};

    #pragma unroll
    for (int i = 0; i < 4; ++i) {
        void* dst = (cloc[i] < 16) ? (void*)&Wlds[0][cloc[i] * 256]
                                   : (void*)&Alds[0][(cloc[i] - 16) * 512];
        gll16(src[i], dst);
        src[i] += stp[i];
    }
    __syncthreads();

    int cur = 0;
    #pragma unroll 1
    for (int s = 0; s < 32; ++s) {
        if (s + 1 < 32) {                            // issue next stage FIRST
            #pragma unroll
            for (int i = 0; i < 4; ++i) {
                void* dst = (cloc[i] < 16) ? (void*)&Wlds[cur ^ 1][cloc[i] * 256]
                                           : (void*)&Alds[cur ^ 1][(cloc[i] - 16) * 512];
                gll16(src[i], dst);
                src[i] += stp[i];
            }
        }
        short8 afr;
        if (isLo) {                                  // lo residual of bf16 split
            #pragma unroll
            for (int e = 0; e < 8; ++e) {
                const float v = Wlds[cur][(lg * 8 + e) * 128 + wv * 16 + l15];
                afr[e] = f2bf(v - bf2f(f2bf(v)));
            }
        } else {
            #pragma unroll
            for (int e = 0; e < 8; ++e)
                afr[e] = f2bf(Wlds[cur][(lg * 8 + e) * 128 + wv * 16 + l15]);
        }
        #pragma unroll
        for (int tt = 0; tt < 16; ++tt) {
            short8 bfr = *reinterpret_cast<const short8*>(
                &Alds[cur][((size_t)lg * 256 + tt * 16 + l15) * 8]);
            acc[tt] = __builtin_amdgcn_mfma_f32_16x16x32_bf16(afr, bfr, acc[tt], 0, 0, 0);
        }
        __syncthreads();
        cur ^= 1;
    }

    if (mainb) {
        // epilogue: z'[t][j] += sum_h C^T[n][t] * S[t][h(n)]
        const int jlo = bn0 / H_SZ;
        #pragma unroll
        for (int tt = 0; tt < 16; ++tt) {
            float p0 = 0.f, p1 = 0.f;
            const int t = tt * 16 + l15;
            #pragma unroll
            for (int r = 0; r < 4; ++r) {
                const int n = bn0 + wv * 16 + lg * 4 + r;
                const bool ok = n < NW;
                const int nc = ok ? n : NW - 1;
                const int j = nc / H_SZ;
                const int h = nc - j * H_SZ;
                const float sv = S[t * H_SZ + h];
                const float prod = ok ? acc[tt][r] * sv : 0.f;
                if (j == jlo) p0 += prod; else p1 += prod;
            }
            p0 += __shfl_xor(p0, 16, 64); p0 += __shfl_xor(p0, 32, 64);
            p1 += __shfl_xor(p1, 16, 64); p1 += __shfl_xor(p1, 32, 64);
            if (lg == 0) {
                if (p0 != 0.f) atomicAdd(&part[0][t], p0);
                if (p1 != 0.f) atomicAdd(&part[1][t], p1);
            }
        }
        __syncthreads();
        const int b = tid >> 8, t = tid & 255;
        const int j = jlo + b;
        const float v = part[b][t];
        if (j < F_SZ && v != 0.f) atomicAdd(&zprime[t * F_SZ + j], v);
    } else {
        float* dst = (mat == 0) ? d1 : ((mat == 1) ? d2h : d2l);
        #pragma unroll
        for (int tt = 0; tt < 16; ++tt) {
            const int t = tt * 16 + l15;
            #pragma unroll
            for (int r = 0; r < 4; ++r) {
                const int n = bn0 + wv * 16 + lg * 4 + r;
                if (n < F_SZ) dst[t * 256 + n] = acc[tt][r];
            }
        }
    }
}

// -------- K4e: z = zprime + d1 + t*(d2h+d2l) + b1 -> SELU -> ysb slab -------
__global__ void __launch_bounds__(256) k4e_selu(const float* __restrict__ zprime,
                                                const float* __restrict__ d1,
                                                const float* __restrict__ d2h,
                                                const float* __restrict__ d2l,
                                                const float* __restrict__ b1,
                                                short* __restrict__ ysb) {
    const int t = blockIdx.x;
    const int j = threadIdx.x;                // 0..255 (250 real + 6 pad)
    short sv = 0;
    if (j < F_SZ) {
        const float d2 = d2h[t * 256 + j] + d2l[t * 256 + j];
        float z = zprime[t * F_SZ + j] + d1[t * 256 + j] + (float)t * d2 + b1[j];
        const float scale = 1.0507009873554805f, alpha = 1.6732632423543772f;
        float y = z > 0.f ? scale * z : scale * alpha * (expf(z) - 1.f);
        sv = f2bf(y);
    }
    ysb[(j >> 3) * (T_SZ * 8) + t * 8 + (j & 7)] = sv;
}

// -------- K4b v2: 256 one-wave blocks (32 o-tiles x 8 t-tiles of 32 t) ------
__global__ void __launch_bounds__(64) k4b_mfma(const short* __restrict__ ysb,
                                               const float* __restrict__ W2,
                                               const float* __restrict__ b2,
                                               float* __restrict__ out) {
    const int l = threadIdx.x;
    const int o0 = (blockIdx.x & 31) * 16;
    const int th = blockIdx.x >> 5;           // 0..7: 32 t each
    const int l15 = l & 15, lg = l >> 4;
    const int o = o0 + l15;

    f32x4 acc[2];
    acc[0] = (f32x4){0.f, 0.f, 0.f, 0.f};
    acc[1] = (f32x4){0.f, 0.f, 0.f, 0.f};

    for (int ks = 0; ks < 8; ++ks) {          // K = 256 (250 real + 6 zero)
        short8 afr;
        #pragma unroll
        for (int e = 0; e < 8; ++e) {
            const int kk = ks * 32 + lg * 8 + e;
            afr[e] = (kk < F_SZ) ? f2bf(W2[kk * O_SZ + o]) : (short)0;
        }
        #pragma unroll
        for (int tt = 0; tt < 2; ++tt) {
            const short* ap = ysb + (size_t)(ks * 4 + lg) * (T_SZ * 8)
                                  + (size_t)(th * 32 + tt * 16 + l15) * 8;
            short8 bfr = *reinterpret_cast<const short8*>(ap);
            acc[tt] = __builtin_amdgcn_mfma_f32_16x16x32_bf16(afr, bfr, acc[tt], 0, 0, 0);
        }
    }
    #pragma unroll
    for (int tt = 0; tt < 2; ++tt) {
        const int t = th * 32 + tt * 16 + l15;
        #pragma unroll
        for (int r = 0; r < 4; ++r) {
            const int oo = o0 + lg * 4 + r;
            out[t * O_SZ + oo] = acc[tt][r] + b2[oo];
        }
    }
}

extern "C" void kernel_launch(void* const* d_in, const int* in_sizes, int n_in,
                              void* d_out, int out_size, void* d_ws, size_t ws_size,
                              hipStream_t stream) {
    const float* x    = (const float*)d_in[0];
    const float* h0   = (const float*)d_in[1];
    const float* Wrnn = (const float*)d_in[2];
    const float* brnn = (const float*)d_in[3];
    const float* Wupd = (const float*)d_in[4];
    const float* bupd = (const float*)d_in[5];
    const float* W1   = (const float*)d_in[6];
    const float* b1   = (const float*)d_in[7];
    const float* W2   = (const float*)d_in[8];
    const float* b2   = (const float*)d_in[9];
    float* out = (float*)d_out;

    float* ws = (float*)d_ws;
    float* P      = ws;                              // 48640 f
    float* S      = P + T_SZ * H_SZ;                 // 48640 f
    float* zprime = S + T_SZ * H_SZ;                 // 64000 f
    short* Abf2   = (short*)(zprime + T_SZ * F_SZ);  // 262144 s (512 KB)
    short* ysb    = Abf2 + 262144;                   // 65536 s (128 KB)
    float* d1     = (float*)(ysb + 65536);           // 65536 f
    float* d2h    = d1 + 65536;                      // 65536 f
    float* d2l    = d2h + 65536;                     // 65536 f
    float* W1p    = d2l + 65536;                     // 262144 f (1 MB)
    float* bupdp  = W1p + 262144;                    // 262144 f (1 MB)

    k2b_buildAx<<<T_SZ, 256, 0, stream>>>(x, W1, bupd, Abf2, zprime, W1p, bupdp);
    k1_mfma    <<<12,   256, 0, stream>>>(Abf2, Wrnn, brnn, P);
    k2_scan    <<<1,    768, 0, stream>>>(Wrnn, h0, P, S, Abf2);
    k3_mfma    <<<378,  512, 0, stream>>>(Wupd, W1p, bupdp, Abf2, S, zprime, d1, d2h, d2l);
    k4e_selu   <<<T_SZ, 256, 0, stream>>>(zprime, d1, d2h, d2l, b1, ysb);
    k4b_mfma   <<<256,  64,  0, stream>>>(ysb, W2, b2, out);
}

// Round 16
// 261.749 us; speedup vs baseline: 1.7045x; 1.1717x over previous
//
#include <hip/hip_runtime.h>
#include <hip/hip_bf16.h>

#define I_SZ 834
#define H_SZ 190
#define F_SZ 250
#define O_SZ 512
#define T_SZ 256
#define K_SZ 1024   // I+H
#define NW   47500  // F*H: Wupd flat IS W3[1024][47500] row-major

// Slab layout (used for Abf2, W2s, Wxs): value M[k][c] lives at
//   (k>>3)*(C*8) + c*8 + (k&7)  (bf16) -> MFMA fragment loads are single
//   b128 per lane, 16 lanes x 16B = 256B coalesced.

typedef __attribute__((ext_vector_type(8))) short short8;
typedef __attribute__((ext_vector_type(4))) float f32x4;

__device__ __forceinline__ short f2bf(float f) {
    union { __hip_bfloat16 h; short s; } u;
    u.h = __float2bfloat16(f);
    return u.s;
}
__device__ __forceinline__ float bf2f(short s) {
    union { short s; __hip_bfloat16 h; } u;
    u.s = s;
    return __bfloat162float(u.h);
}

// async global->LDS, 16B per lane; LDS dest = wave-uniform base + lane*16
__device__ __forceinline__ void gll16(const void* g, void* l) {
    __builtin_amdgcn_global_load_lds(
        (const __attribute__((address_space(1))) void*)g,
        (__attribute__((address_space(3))) void*)l, 16, 0, 0);
}

// LDS-only barrier: drain lgkm (ds ops) but NOT vmcnt.
__device__ __forceinline__ void lds_barrier() {
    asm volatile("s_waitcnt lgkmcnt(0)" ::: "memory");
    __builtin_amdgcn_s_barrier();
}

// branch-free tanh: 1 - 2/(e^{2x}+1); exp overflow/underflow saturate to +/-1
__device__ __forceinline__ float fast_tanh(float x) {
    const float e = __expf(2.f * x);
    return 1.f - 2.f / (e + 1.f);
}

// -------- K2b: x->Abf2 slab + zprime zero + W1/bupd pad + W2s/Wxs slabs -----
__global__ void __launch_bounds__(256) k2b_buildAx(const float* __restrict__ x,
                                                   const float* __restrict__ W1,
                                                   const float* __restrict__ bupd,
                                                   const float* __restrict__ W2,
                                                   const float* __restrict__ Wrnn,
                                                   short* __restrict__ Abf2,
                                                   float* __restrict__ zprime,
                                                   float* __restrict__ W1p,
                                                   float* __restrict__ bupdp,
                                                   short* __restrict__ W2s,
                                                   short* __restrict__ Wxs) {
    const int t = blockIdx.x;
    const int c = threadIdx.x;
    for (int i = c; i < I_SZ; i += 256)
        Abf2[(i >> 3) * (T_SZ * 8) + t * 8 + (i & 7)] = f2bf(x[t * I_SZ + i]);
    for (int i = I_SZ + c; i < 864; i += 256)
        Abf2[(i >> 3) * (T_SZ * 8) + t * 8 + (i & 7)] = 0;
    for (int j = c; j < F_SZ; j += 256)
        zprime[t * F_SZ + j] = 0.f;
    // pad W1/bupd to 256 cols (rows 4t..4t+3)
    #pragma unroll
    for (int rr = 0; rr < 4; ++rr) {
        const int r = t * 4 + rr;           // 0..1023
        W1p[r * 256 + c]   = (c < F_SZ) ? W1[r * F_SZ + c] : 0.f;
        bupdp[r * 256 + c] = (c < F_SZ) ? bupd[r * F_SZ + c] : 0.f;
    }
    // W2s slab: j-row = t (zeros for t>=250), o in [0,512)
    {
        const int j = t;
        #pragma unroll
        for (int rep = 0; rep < 2; ++rep) {
            const int o = c + rep * 256;
            W2s[(j >> 3) * (O_SZ * 8) + o * 8 + (j & 7)] =
                (j < F_SZ) ? f2bf(W2[j * O_SZ + o]) : (short)0;
        }
    }
    // Wxs slab: kk-slab s = t (s < 108), h in [0,192)
    if (t < 108) {
        const int h = c;
        if (h < 192) {
            #pragma unroll
            for (int e = 0; e < 8; ++e) {
                const int kk = t * 8 + e;
                const float v = (h < H_SZ && kk < I_SZ) ? Wrnn[h * K_SZ + H_SZ + kk] : 0.f;
                Wxs[t * 1536 + h * 8 + e] = f2bf(v);
            }
        }
    }
}

// -------- K1 v3: P^T[h][t] via MFMA; A-frags = b128 slab loads from Wxs -----
__global__ void __launch_bounds__(256) k1_mfma(const short* __restrict__ Abf2,
                                               const short* __restrict__ Wxs,
                                               const float* __restrict__ brnn,
                                               float* __restrict__ P) {
    const int tid = threadIdx.x;
    const int bh = blockIdx.x;
    const int w = tid >> 6, l = tid & 63;
    const int l15 = l & 15, lg = l >> 4;

    f32x4 acc[4];
    #pragma unroll
    for (int tt = 0; tt < 4; ++tt) acc[tt] = (f32x4){0.f, 0.f, 0.f, 0.f};

    for (int ks = 0; ks < 27; ++ks) {       // K = 864 (zero-padded past 834)
        const short8 afr = *reinterpret_cast<const short8*>(
            &Wxs[(size_t)(ks * 4 + lg) * 1536 + (size_t)(bh * 16 + l15) * 8]);
        #pragma unroll
        for (int tt = 0; tt < 4; ++tt) {
            const short* ap = Abf2 + (size_t)(ks * 4 + lg) * (T_SZ * 8)
                                   + (size_t)(w * 64 + tt * 16 + l15) * 8;
            short8 bfr = *reinterpret_cast<const short8*>(ap);
            acc[tt] = __builtin_amdgcn_mfma_f32_16x16x32_bf16(afr, bfr, acc[tt], 0, 0, 0);
        }
    }
    #pragma unroll
    for (int tt = 0; tt < 4; ++tt) {
        const int t = w * 64 + tt * 16 + l15;
        #pragma unroll
        for (int r = 0; r < 4; ++r) {
            const int hrow = bh * 16 + lg * 4 + r;
            if (hrow < H_SZ) P[t * H_SZ + hrow] = acc[tt][r] + brnn[hrow];
        }
    }
}

// -------- K2 v6 (round-12 validated, 167 us): 12 waves x 16 n-cols ----------
__global__ void __launch_bounds__(768, 1) k2_scan(const float* __restrict__ Wrnn,
                                                  const float* __restrict__ h0,
                                                  const float* __restrict__ P,
                                                  float* __restrict__ S,
                                                  short* __restrict__ Abf2) {
    __shared__ __align__(16) short hlds[2][192];
    const int tid = threadIdx.x;
    const int w = tid >> 6, l = tid & 63;
    const int l15 = l & 15, lg = l >> 4;
    const short8 zs = {0, 0, 0, 0, 0, 0, 0, 0};
    const int n = w * 16 + l15;             // wave w owns n-cols [w*16, w*16+16)
    const bool nok = n < H_SZ;

    short8 B[6];
    #pragma unroll
    for (int kt = 0; kt < 6; ++kt) {
        short8 bf = zs;
        #pragma unroll
        for (int e = 0; e < 8; ++e) {
            const int kk = kt * 32 + lg * 8 + e;
            float v = (nok && kk < H_SZ) ? Wrnn[n * K_SZ + kk] : 0.f;
            bf[e] = f2bf(v);
        }
        B[kt] = bf;
    }
    if (tid < 192) {
        hlds[0][tid] = f2bf((tid < H_SZ) ? h0[tid] : 0.f);
        hlds[1][tid] = 0;                   // pad slots 190,191 stay 0 forever
    }
    float Srun = 0.f;
    float pc = (l < 16 && nok) ? P[n] : 0.f;
    lds_barrier();

    int rb = 0;
    #pragma unroll 1
    for (int t = 0; t < T_SZ; ++t) {
        short8 a[6];
        #pragma unroll
        for (int kt = 0; kt < 6; ++kt) {
            short8 ar = *reinterpret_cast<const short8*>(&hlds[rb][kt * 32 + lg * 8]);
            a[kt] = (l15 == 0) ? ar : zs;
        }
        const float pn = (t + 1 < T_SZ && l < 16 && nok) ? P[(t + 1) * H_SZ + n] : 0.f;
        f32x4 c[6];
        #pragma unroll
        for (int kt = 0; kt < 6; ++kt) {
            const f32x4 z4 = {0.f, 0.f, 0.f, 0.f};
            c[kt] = __builtin_amdgcn_mfma_f32_16x16x32_bf16(a[kt], B[kt], z4, 0, 0, 0);
        }
        if (l < 16 && nok) {
            const float s = ((c[0][0] + c[1][0]) + (c[2][0] + c[3][0]))
                          + (c[4][0] + c[5][0]) + pc;
            const float v = fast_tanh(s);
            S[t * H_SZ + n] = Srun;         // prefix EXCLUDING current step
            const int k = I_SZ + n;
            Abf2[(k >> 3) * (T_SZ * 8) + t * 8 + (k & 7)] = f2bf(v);
            hlds[rb ^ 1][n] = f2bf(v);      // write buffer != read buffer
            Srun += v;
        }
        lds_barrier();                      // single LDS-only barrier per step
        rb ^= 1;
        pc = pn;
    }
}

// -------- K3 v6b: staged MFMA GEMM; blocks 0..371 = Wupd (S-contract fused),
// blocks 372..377 = W1p / bupdp_hi / bupdp_lo (padded, stride 256).
__global__ void __launch_bounds__(512) k3_mfma(const float* __restrict__ Wupd,
                                               const float* __restrict__ W1p,
                                               const float* __restrict__ bupdp,
                                               const short* __restrict__ Abf2,
                                               const float* __restrict__ S,
                                               float* __restrict__ zprime,
                                               float* __restrict__ d1,
                                               float* __restrict__ d2h,
                                               float* __restrict__ d2l) {
    __shared__ __align__(16) float Wlds[2][4096];    // [32 k][128 n] fp32
    __shared__ __align__(16) short Alds[2][8192];    // [4 g][256 t][8 k] bf16
    __shared__ float part[2][256];
    const int tid = threadIdx.x;
    const int bid = blockIdx.x;
    const bool mainb = bid < 372;
    const int role = mainb ? 0 : (bid - 372);        // 0,1:W1  2,3:hi  4,5:lo
    const int mat  = role >> 1;
    const bool isLo = (!mainb) && (mat == 2);
    const float* Wsrc = mainb ? Wupd : ((mat == 0) ? W1p : bupdp);
    const int stride  = mainb ? NW : 256;
    const int ncols   = mainb ? NW : 256;
    const int bn0     = mainb ? bid * 128 : (role & 1) * 128;
    const int l = tid & 63, wv = tid >> 6;
    const int l15 = l & 15, lg = l >> 4;

    part[tid >> 8][tid & 255] = 0.f;

    const char* src[4];
    long long stp[4];
    int cloc[4];
    #pragma unroll
    for (int i = 0; i < 4; ++i) {
        const int c = wv * 4 + i;
        cloc[i] = c;
        if (c < 16) {
            const int k = c * 2 + (l >> 5);          // 0..31
            const int n = (l & 31) * 4;              // 0..124
            const bool ok = (bn0 + n + 4) <= ncols;  // ncols % 4 == 0 both paths
            src[i] = (const char*)(Wsrc + (size_t)k * stride + (ok ? (size_t)(bn0 + n) : 0));
            stp[i] = (long long)32 * stride * 4;
        } else {
            src[i] = (const char*)(Abf2 + (size_t)(c - 16) * 512 + (size_t)l * 8);
            stp[i] = 16384;
        }
    }

    f32x4 acc[16];
    #pragma unroll
    for (int tt = 0; tt < 16; ++tt) acc[tt] = (f32x4){0.f, 0.f, 0.f, 0.f};

    #pragma unroll
    for (int i = 0; i < 4; ++i) {
        void* dst = (cloc[i] < 16) ? (void*)&Wlds[0][cloc[i] * 256]
                                   : (void*)&Alds[0][(cloc[i] - 16) * 512];
        gll16(src[i], dst);
        src[i] += stp[i];
    }
    __syncthreads();

    int cur = 0;
    #pragma unroll 1
    for (int s = 0; s < 32; ++s) {
        if (s + 1 < 32) {                            // issue next stage FIRST
            #pragma unroll
            for (int i = 0; i < 4; ++i) {
                void* dst = (cloc[i] < 16) ? (void*)&Wlds[cur ^ 1][cloc[i] * 256]
                                           : (void*)&Alds[cur ^ 1][(cloc[i] - 16) * 512];
                gll16(src[i], dst);
                src[i] += stp[i];
            }
        }
        short8 afr;
        if (isLo) {                                  // lo residual of bf16 split
            #pragma unroll
            for (int e = 0; e < 8; ++e) {
                const float v = Wlds[cur][(lg * 8 + e) * 128 + wv * 16 + l15];
                afr[e] = f2bf(v - bf2f(f2bf(v)));
            }
        } else {
            #pragma unroll
            for (int e = 0; e < 8; ++e)
                afr[e] = f2bf(Wlds[cur][(lg * 8 + e) * 128 + wv * 16 + l15]);
        }
        #pragma unroll
        for (int tt = 0; tt < 16; ++tt) {
            short8 bfr = *reinterpret_cast<const short8*>(
                &Alds[cur][((size_t)lg * 256 + tt * 16 + l15) * 8]);
            acc[tt] = __builtin_amdgcn_mfma_f32_16x16x32_bf16(afr, bfr, acc[tt], 0, 0, 0);
        }
        __syncthreads();
        cur ^= 1;
    }

    if (mainb) {
        // epilogue: z'[t][j] += sum_h C^T[n][t] * S[t][h(n)]
        const int jlo = bn0 / H_SZ;
        #pragma unroll
        for (int tt = 0; tt < 16; ++tt) {
            float p0 = 0.f, p1 = 0.f;
            const int t = tt * 16 + l15;
            #pragma unroll
            for (int r = 0; r < 4; ++r) {
                const int n = bn0 + wv * 16 + lg * 4 + r;
                const bool ok = n < NW;
                const int nc = ok ? n : NW - 1;
                const int j = nc / H_SZ;
                const int h = nc - j * H_SZ;
                const float sv = S[t * H_SZ + h];
                const float prod = ok ? acc[tt][r] * sv : 0.f;
                if (j == jlo) p0 += prod; else p1 += prod;
            }
            p0 += __shfl_xor(p0, 16, 64); p0 += __shfl_xor(p0, 32, 64);
            p1 += __shfl_xor(p1, 16, 64); p1 += __shfl_xor(p1, 32, 64);
            if (lg == 0) {
                if (p0 != 0.f) atomicAdd(&part[0][t], p0);
                if (p1 != 0.f) atomicAdd(&part[1][t], p1);
            }
        }
        __syncthreads();
        const int b = tid >> 8, t = tid & 255;
        const int j = jlo + b;
        const float v = part[b][t];
        if (j < F_SZ && v != 0.f) atomicAdd(&zprime[t * F_SZ + j], v);
    } else {
        float* dst = (mat == 0) ? d1 : ((mat == 1) ? d2h : d2l);
        #pragma unroll
        for (int tt = 0; tt < 16; ++tt) {
            const int t = tt * 16 + l15;
            #pragma unroll
            for (int r = 0; r < 4; ++r) {
                const int n = bn0 + wv * 16 + lg * 4 + r;
                if (n < F_SZ) dst[t * 256 + n] = acc[tt][r];
            }
        }
    }
}

// -------- K4e: z = zprime + d1 + t*(d2h+d2l) + b1 -> SELU -> ysb slab -------
__global__ void __launch_bounds__(256) k4e_selu(const float* __restrict__ zprime,
                                                const float* __restrict__ d1,
                                                const float* __restrict__ d2h,
                                                const float* __restrict__ d2l,
                                                const float* __restrict__ b1,
                                                short* __restrict__ ysb) {
    const int t = blockIdx.x;
    const int j = threadIdx.x;                // 0..255 (250 real + 6 pad)
    short sv = 0;
    if (j < F_SZ) {
        const float d2 = d2h[t * 256 + j] + d2l[t * 256 + j];
        float z = zprime[t * F_SZ + j] + d1[t * 256 + j] + (float)t * d2 + b1[j];
        const float scale = 1.0507009873554805f, alpha = 1.6732632423543772f;
        float y = z > 0.f ? scale * z : scale * alpha * (expf(z) - 1.f);
        sv = f2bf(y);
    }
    ysb[(j >> 3) * (T_SZ * 8) + t * 8 + (j & 7)] = sv;
}

// -------- K4b v3: A-frags = b128 slab loads from W2s (no scattered gathers) -
__global__ void __launch_bounds__(64) k4b_mfma(const short* __restrict__ ysb,
                                               const short* __restrict__ W2s,
                                               const float* __restrict__ b2,
                                               float* __restrict__ out) {
    const int l = threadIdx.x;
    const int o0 = (blockIdx.x & 31) * 16;
    const int th = blockIdx.x >> 5;           // 0..7: 32 t each
    const int l15 = l & 15, lg = l >> 4;
    const int o = o0 + l15;

    f32x4 acc[2];
    acc[0] = (f32x4){0.f, 0.f, 0.f, 0.f};
    acc[1] = (f32x4){0.f, 0.f, 0.f, 0.f};

    #pragma unroll
    for (int ks = 0; ks < 8; ++ks) {          // K = 256 (250 real + 6 zero)
        const short8 afr = *reinterpret_cast<const short8*>(
            &W2s[(size_t)(ks * 4 + lg) * (O_SZ * 8) + (size_t)o * 8]);
        #pragma unroll
        for (int tt = 0; tt < 2; ++tt) {
            const short* ap = ysb + (size_t)(ks * 4 + lg) * (T_SZ * 8)
                                  + (size_t)(th * 32 + tt * 16 + l15) * 8;
            short8 bfr = *reinterpret_cast<const short8*>(ap);
            acc[tt] = __builtin_amdgcn_mfma_f32_16x16x32_bf16(afr, bfr, acc[tt], 0, 0, 0);
        }
    }
    #pragma unroll
    for (int tt = 0; tt < 2; ++tt) {
        const int t = th * 32 + tt * 16 + l15;
        #pragma unroll
        for (int r = 0; r < 4; ++r) {
            const int oo = o0 + lg * 4 + r;
            out[t * O_SZ + oo] = acc[tt][r] + b2[oo];
        }
    }
}

extern "C" void kernel_launch(void* const* d_in, const int* in_sizes, int n_in,
                              void* d_out, int out_size, void* d_ws, size_t ws_size,
                              hipStream_t stream) {
    const float* x    = (const float*)d_in[0];
    const float* h0   = (const float*)d_in[1];
    const float* Wrnn = (const float*)d_in[2];
    const float* brnn = (const float*)d_in[3];
    const float* Wupd = (const float*)d_in[4];
    const float* bupd = (const float*)d_in[5];
    const float* W1   = (const float*)d_in[6];
    const float* b1   = (const float*)d_in[7];
    const float* W2   = (const float*)d_in[8];
    const float* b2   = (const float*)d_in[9];
    float* out = (float*)d_out;

    float* ws = (float*)d_ws;
    float* P      = ws;                              // 48640 f
    float* S      = P + T_SZ * H_SZ;                 // 48640 f
    float* zprime = S + T_SZ * H_SZ;                 // 64000 f
    short* Abf2   = (short*)(zprime + T_SZ * F_SZ);  // 262144 s (512 KB)
    short* ysb    = Abf2 + 262144;                   // 65536 s (128 KB)
    float* d1     = (float*)(ysb + 65536);           // 65536 f
    float* d2h    = d1 + 65536;                      // 65536 f
    float* d2l    = d2h + 65536;                     // 65536 f
    float* W1p    = d2l + 65536;                     // 262144 f (1 MB)
    float* bupdp  = W1p + 262144;                    // 262144 f (1 MB)
    short* W2s    = (short*)(bupdp + 262144);        // 131072 s (256 KB)
    short* Wxs    = W2s + 131072;                    // 165888 s (324 KB)

    k2b_buildAx<<<T_SZ, 256, 0, stream>>>(x, W1, bupd, W2, Wrnn,
                                          Abf2, zprime, W1p, bupdp, W2s, Wxs);
    k1_mfma    <<<12,   256, 0, stream>>>(Abf2, Wxs, brnn, P);
    k2_scan    <<<1,    768, 0, stream>>>(Wrnn, h0, P, S, Abf2);
    k3_mfma    <<<378,  512, 0, stream>>>(Wupd, W1p, bupdp, Abf2, S, zprime, d1, d2h, d2l);
    k4e_selu   <<<T_SZ, 256, 0, stream>>>(zprime, d1, d2h, d2l, b1, ysb);
    k4b_mfma   <<<256,  64,  0, stream>>>(ysb, W2s, b2, out);
}